// Round 1
// baseline (160.318 us; speedup 1.0000x reference)
//
#include <hip/hip_runtime.h>
#include <math.h>

// Problem constants (from reference): N=1e6 points, C=64 clusters, D=3.
#define NCLUS 64
#define BLOCK 256

// ws layout (floats):
//  [0,64)    counts
//  [64,256)  coord sums  [c*3+d]
//  [256,320) margin sums
//  [320,576) params      [c*4]: cx, cy, cz, 1/(2*sigma^2)
//  [576,640) sigma[c]
// doubles at (float*)ws + 640: acc[0]=bce_sum, acc[1]=seed_sum, acc[2]=smooth_sum

__global__ void init_ws_kernel(float* f) {
    int i = blockIdx.x * blockDim.x + threadIdx.x;
    if (i < 320) f[i] = 0.0f;
    if (i < 3) ((double*)(f + 640))[i] = 0.0;
}

__global__ void cluster_sums_kernel(const float* __restrict__ coords,
                                    const float* __restrict__ margins,
                                    const int* __restrict__ labels,
                                    int n, float* __restrict__ f) {
    __shared__ float s_cnt[NCLUS];
    __shared__ float s_sum[NCLUS * 3];
    __shared__ float s_m[NCLUS];
    for (int i = threadIdx.x; i < NCLUS; i += blockDim.x) { s_cnt[i] = 0.f; s_m[i] = 0.f; }
    for (int i = threadIdx.x; i < NCLUS * 3; i += blockDim.x) s_sum[i] = 0.f;
    __syncthreads();

    for (int i = blockIdx.x * blockDim.x + threadIdx.x; i < n;
         i += gridDim.x * blockDim.x) {
        int lab = labels[i];
        atomicAdd(&s_cnt[lab], 1.0f);
        atomicAdd(&s_sum[lab * 3 + 0], coords[i * 3 + 0]);
        atomicAdd(&s_sum[lab * 3 + 1], coords[i * 3 + 1]);
        atomicAdd(&s_sum[lab * 3 + 2], coords[i * 3 + 2]);
        atomicAdd(&s_m[lab], margins[i]);
    }
    __syncthreads();

    for (int i = threadIdx.x; i < NCLUS; i += blockDim.x) {
        atomicAdd(&f[i], s_cnt[i]);
        atomicAdd(&f[256 + i], s_m[i]);
    }
    for (int i = threadIdx.x; i < NCLUS * 3; i += blockDim.x)
        atomicAdd(&f[64 + i], s_sum[i]);
}

__global__ void compute_params_kernel(float* f) {
    int c = threadIdx.x;
    if (c < NCLUS) {
        float inv = 1.0f / f[c];                  // 1/count
        float sigma = f[256 + c] * inv;           // mean margin
        f[320 + c * 4 + 0] = f[64 + c * 3 + 0] * inv;
        f[320 + c * 4 + 1] = f[64 + c * 3 + 1] * inv;
        f[320 + c * 4 + 2] = f[64 + c * 3 + 2] * inv;
        f[320 + c * 4 + 3] = 1.0f / (2.0f * sigma * sigma);
        f[576 + c] = sigma;
    }
}

__global__ void main_loss_kernel(const float* __restrict__ emb,
                                 const float* __restrict__ margins,
                                 const float* __restrict__ seed,
                                 const int* __restrict__ labels,
                                 int n, const float* __restrict__ f,
                                 double* __restrict__ acc) {
    __shared__ float4 s_par[NCLUS];   // cx,cy,cz,inv2sig2
    __shared__ float s_sig[NCLUS];
    __shared__ float s_red[BLOCK / 64];

    if (threadIdx.x < NCLUS) {
        s_par[threadIdx.x] = ((const float4*)(f + 320))[threadIdx.x];
        s_sig[threadIdx.x] = f[576 + threadIdx.x];
    }
    __syncthreads();

    float bce_sum = 0.f, seed_sum = 0.f, smooth_sum = 0.f;

    for (int i = blockIdx.x * blockDim.x + threadIdx.x; i < n;
         i += gridDim.x * blockDim.x) {
        float ex = emb[i * 3 + 0], ey = emb[i * 3 + 1], ez = emb[i * 3 + 2];
        int lab = labels[i];
        float prob = 0.f;
#pragma unroll 16
        for (int c = 0; c < NCLUS; ++c) {
            float4 pr = s_par[c];
            float dx = ex - pr.x, dy = ey - pr.y, dz = ez - pr.z;
            float dist = dx * dx + dy * dy + dz * dz;
            float p = __expf(-dist * pr.w);
            p = fminf(p, 1.0f);                       // clip to [0,1]; p>=0 already
            float sp = __logf(1.0f + __expf(-p));     // log1p(exp(-|p|)), p>=0
            bool is = (c == lab);
            bce_sum += p - (is ? p : 0.0f) + sp;
            prob = is ? p : prob;
        }
        float m = margins[i];
        float ds = m - s_sig[lab];
        smooth_sum += ds * ds;
        seed_sum += fabsf(prob - seed[i]);
    }

    // block reduce the three partials
    float vals[3] = {bce_sum, seed_sum, smooth_sum};
    int lane = threadIdx.x & 63;
    int wid = threadIdx.x >> 6;
#pragma unroll
    for (int k = 0; k < 3; ++k) {
        float v = vals[k];
        for (int o = 32; o > 0; o >>= 1) v += __shfl_down(v, o);
        if (wid == 0) s_red[lane < (BLOCK / 64) ? lane : 0] = 0.f;  // placeholder
        __syncthreads();
        if (lane == 0) s_red[wid] = v;
        __syncthreads();
        if (threadIdx.x == 0) {
            float t = 0.f;
            for (int w = 0; w < BLOCK / 64; ++w) t += s_red[w];
            atomicAdd(&acc[k], (double)t);
        }
        __syncthreads();
    }
}

__global__ void finalize_kernel(const double* __restrict__ acc,
                                float* __restrict__ out, int n) {
    double mask_loss = acc[0] / ((double)NCLUS * (double)n);
    double seed_loss = acc[1] / (double)n;
    double smooth_loss = acc[2] / (double)NCLUS;
    out[0] = (float)(mask_loss + seed_loss + smooth_loss);
}

extern "C" void kernel_launch(void* const* d_in, const int* in_sizes, int n_in,
                              void* d_out, int out_size, void* d_ws, size_t ws_size,
                              hipStream_t stream) {
    const float* emb     = (const float*)d_in[0];
    const float* margins = (const float*)d_in[1];
    const float* seed    = (const float*)d_in[2];
    const float* coords  = (const float*)d_in[3];
    const int*   labels  = (const int*)d_in[4];
    int n = in_sizes[4];   // N = label count

    float* f = (float*)d_ws;
    double* acc = (double*)(f + 640);
    float* out = (float*)d_out;

    init_ws_kernel<<<1, 512, 0, stream>>>(f);

    int grid_sums = (n + BLOCK - 1) / BLOCK;
    if (grid_sums > 2048) grid_sums = 2048;
    cluster_sums_kernel<<<grid_sums, BLOCK, 0, stream>>>(coords, margins, labels, n, f);

    compute_params_kernel<<<1, 64, 0, stream>>>(f);

    int grid_main = (n + BLOCK - 1) / BLOCK;
    if (grid_main > 2048) grid_main = 2048;
    main_loss_kernel<<<grid_main, BLOCK, 0, stream>>>(emb, margins, seed, labels, n, f, acc);

    finalize_kernel<<<1, 1, 0, stream>>>(acc, out, n);
}

// Round 2
// 113.407 us; speedup vs baseline: 1.4137x; 1.4137x over previous
//
#include <hip/hip_runtime.h>
#include <math.h>

#define NCLUS 64
#define BLOCK 256

#if __has_builtin(__builtin_amdgcn_exp2f)
#define EXP2F(x) __builtin_amdgcn_exp2f(x)
#else
#define EXP2F(x) __expf(0.6931471805599453f * (x))
#endif

// degree-4 poly for softplus(p) = log(1+exp(p)) on p in [0,1], err ~2e-6
#define SP_C0 0.69314718f
#define SP_C1 0.49991956f
#define SP_C2 0.12562243f
#define SP_C3 -0.00152320f
#define SP_C4 -0.00390297f

__device__ __forceinline__ float softplus01(float p) {
    return fmaf(p, fmaf(p, fmaf(p, fmaf(p, SP_C4, SP_C3), SP_C2), SP_C1), SP_C0);
}

// ws layout (floats):
//  [0,64)    counts
//  [64,256)  coord sums [c*3+d]
//  [256,320) margin sums
//  [320,576) params [c*4]: cx, cy, cz, w2 = -log2(e)/(2*sigma^2)
//  [576,640) sigma[c]
// doubles at f+640: acc[0]=bce, acc[1]=seed, acc[2]=smooth

__global__ void init_ws_kernel(float* f) {
    int i = blockIdx.x * blockDim.x + threadIdx.x;
    if (i < 320) f[i] = 0.0f;
    if (i < 3) ((double*)(f + 640))[i] = 0.0;
}

__global__ void cluster_sums_kernel(const float* __restrict__ coords,
                                    const float* __restrict__ margins,
                                    const int* __restrict__ labels,
                                    int n, float* __restrict__ f) {
    // 8 replicas: (wave id 0..3) x (lane parity) to cut same-address atomic serialization
    __shared__ float s_h[8][5][NCLUS];
    for (int i = threadIdx.x; i < 8 * 5 * NCLUS; i += blockDim.x)
        ((float*)s_h)[i] = 0.0f;
    __syncthreads();

    const int rep = ((threadIdx.x >> 6) << 1) | (threadIdx.x & 1);
    const int chunks = n >> 2;
    const int stride = gridDim.x * blockDim.x;
    const float4* c4 = (const float4*)coords;
    const float4* m4 = (const float4*)margins;
    const int4* l4 = (const int4*)labels;

    for (int ch = blockIdx.x * blockDim.x + threadIdx.x; ch < chunks; ch += stride) {
        float4 e0 = c4[ch * 3 + 0], e1 = c4[ch * 3 + 1], e2 = c4[ch * 3 + 2];
        float4 mg = m4[ch];
        int4 lb = l4[ch];
        float x[4] = {e0.x, e0.w, e1.z, e2.y};
        float y[4] = {e0.y, e1.x, e1.w, e2.z};
        float z[4] = {e0.z, e1.y, e2.x, e2.w};
        float m[4] = {mg.x, mg.y, mg.z, mg.w};
        int   l[4] = {lb.x, lb.y, lb.z, lb.w};
#pragma unroll
        for (int k = 0; k < 4; ++k) {
            atomicAdd(&s_h[rep][0][l[k]], 1.0f);
            atomicAdd(&s_h[rep][1][l[k]], x[k]);
            atomicAdd(&s_h[rep][2][l[k]], y[k]);
            atomicAdd(&s_h[rep][3][l[k]], z[k]);
            atomicAdd(&s_h[rep][4][l[k]], m[k]);
        }
    }

    // scalar tail (n % 4 points), handled by first threads of the grid
    int rem = n & 3;
    int gid = blockIdx.x * blockDim.x + threadIdx.x;
    if (gid < rem) {
        int i = (chunks << 2) + gid;
        int lab = labels[i];
        atomicAdd(&s_h[rep][0][lab], 1.0f);
        atomicAdd(&s_h[rep][1][lab], coords[i * 3 + 0]);
        atomicAdd(&s_h[rep][2][lab], coords[i * 3 + 1]);
        atomicAdd(&s_h[rep][3][lab], coords[i * 3 + 2]);
        atomicAdd(&s_h[rep][4][lab], margins[i]);
    }
    __syncthreads();

    for (int idx = threadIdx.x; idx < 5 * NCLUS; idx += blockDim.x) {
        int field = idx >> 6, c = idx & 63;
        float v = 0.0f;
#pragma unroll
        for (int r = 0; r < 8; ++r) v += s_h[r][field][c];
        int dest = (field == 0) ? c : (field <= 3 ? 64 + c * 3 + (field - 1) : 256 + c);
        atomicAdd(&f[dest], v);
    }
}

__global__ void compute_params_kernel(float* f) {
    int c = threadIdx.x;
    if (c < NCLUS) {
        float inv = 1.0f / f[c];
        float sigma = f[256 + c] * inv;
        f[320 + c * 4 + 0] = f[64 + c * 3 + 0] * inv;
        f[320 + c * 4 + 1] = f[64 + c * 3 + 1] * inv;
        f[320 + c * 4 + 2] = f[64 + c * 3 + 2] * inv;
        f[320 + c * 4 + 3] = -1.4426950408889634f / (2.0f * sigma * sigma);
        f[576 + c] = sigma;
    }
}

__device__ __forceinline__ float block_reduce_sum(float v, float* s_red) {
    for (int o = 32; o > 0; o >>= 1) v += __shfl_down(v, o);
    int lane = threadIdx.x & 63, wid = threadIdx.x >> 6;
    __syncthreads();
    if (lane == 0) s_red[wid] = v;
    __syncthreads();
    float t = 0.0f;
    if (threadIdx.x == 0)
        for (int w = 0; w < BLOCK / 64; ++w) t += s_red[w];
    return t;  // valid on thread 0 only
}

__global__ __launch_bounds__(BLOCK) void main_loss_kernel(
        const float* __restrict__ emb, const float* __restrict__ margins,
        const float* __restrict__ seed, const int* __restrict__ labels,
        int n, const float* __restrict__ f, double* __restrict__ acc) {
    __shared__ float4 s_par[NCLUS];  // cx,cy,cz,w2
    __shared__ float s_sig[NCLUS];
    __shared__ float s_red[BLOCK / 64];

    if (threadIdx.x < NCLUS) {
        s_par[threadIdx.x] = ((const float4*)(f + 320))[threadIdx.x];
        s_sig[threadIdx.x] = f[576 + threadIdx.x];
    }
    __syncthreads();

    const int chunks = n >> 2;
    const int stride = gridDim.x * blockDim.x;
    const float4* e4 = (const float4*)emb;
    const float4* m4 = (const float4*)margins;
    const float4* s4 = (const float4*)seed;
    const int4* l4 = (const int4*)labels;

    float bce = 0.0f, seed_s = 0.0f, smooth_s = 0.0f;

    for (int ch = blockIdx.x * blockDim.x + threadIdx.x; ch < chunks; ch += stride) {
        float4 e0 = e4[ch * 3 + 0], e1 = e4[ch * 3 + 1], e2 = e4[ch * 3 + 2];
        float x[4] = {e0.x, e0.w, e1.z, e2.y};
        float y[4] = {e0.y, e1.x, e1.w, e2.z};
        float z[4] = {e0.z, e1.y, e2.x, e2.w};
        int4 lb = l4[ch];
        float4 mg = m4[ch];
        float4 sd = s4[ch];
        int   l[4] = {lb.x, lb.y, lb.z, lb.w};
        float m[4] = {mg.x, mg.y, mg.z, mg.w};
        float s[4] = {sd.x, sd.y, sd.z, sd.w};

        float a[4] = {0.f, 0.f, 0.f, 0.f};
#pragma unroll 16
        for (int c = 0; c < NCLUS; ++c) {
            float4 pr = s_par[c];
#pragma unroll
            for (int k = 0; k < 4; ++k) {
                float dx = x[k] - pr.x, dy = y[k] - pr.y, dz = z[k] - pr.z;
                float d = fmaf(dx, dx, fmaf(dy, dy, dz * dz));
                float p = EXP2F(d * pr.w);
                a[k] += softplus01(p);
            }
        }
        bce += (a[0] + a[1]) + (a[2] + a[3]);

        // own-cluster prob, seediness, smoothing
#pragma unroll
        for (int k = 0; k < 4; ++k) {
            float4 pr = s_par[l[k]];
            float dx = x[k] - pr.x, dy = y[k] - pr.y, dz = z[k] - pr.z;
            float d = fmaf(dx, dx, fmaf(dy, dy, dz * dz));
            float p = EXP2F(d * pr.w);
            bce -= p;
            seed_s += fabsf(p - s[k]);
            float dsg = m[k] - s_sig[l[k]];
            smooth_s += dsg * dsg;
        }
    }

    // scalar tail
    int rem = n & 3;
    int gid = blockIdx.x * blockDim.x + threadIdx.x;
    if (gid < rem) {
        int i = (chunks << 2) + gid;
        float ex = emb[i * 3 + 0], ey = emb[i * 3 + 1], ez = emb[i * 3 + 2];
        int lab = labels[i];
        float pl = 0.0f;
        for (int c = 0; c < NCLUS; ++c) {
            float4 pr = s_par[c];
            float dx = ex - pr.x, dy = ey - pr.y, dz = ez - pr.z;
            float d = fmaf(dx, dx, fmaf(dy, dy, dz * dz));
            float p = EXP2F(d * pr.w);
            bce += softplus01(p);
            if (c == lab) pl = p;
        }
        bce -= pl;
        seed_s += fabsf(pl - seed[i]);
        float dsg = margins[i] - s_sig[lab];
        smooth_s += dsg * dsg;
    }

    float r;
    r = block_reduce_sum(bce, s_red);
    if (threadIdx.x == 0) atomicAdd(&acc[0], (double)r);
    r = block_reduce_sum(seed_s, s_red);
    if (threadIdx.x == 0) atomicAdd(&acc[1], (double)r);
    r = block_reduce_sum(smooth_s, s_red);
    if (threadIdx.x == 0) atomicAdd(&acc[2], (double)r);
}

__global__ void finalize_kernel(const double* __restrict__ acc,
                                float* __restrict__ out, int n) {
    double mask_loss = acc[0] / ((double)NCLUS * (double)n);
    double seed_loss = acc[1] / (double)n;
    double smooth_loss = acc[2] / (double)NCLUS;
    out[0] = (float)(mask_loss + seed_loss + smooth_loss);
}

extern "C" void kernel_launch(void* const* d_in, const int* in_sizes, int n_in,
                              void* d_out, int out_size, void* d_ws, size_t ws_size,
                              hipStream_t stream) {
    const float* emb     = (const float*)d_in[0];
    const float* margins = (const float*)d_in[1];
    const float* seed    = (const float*)d_in[2];
    const float* coords  = (const float*)d_in[3];
    const int*   labels  = (const int*)d_in[4];
    int n = in_sizes[4];

    float* f = (float*)d_ws;
    double* acc = (double*)(f + 640);
    float* out = (float*)d_out;

    init_ws_kernel<<<1, 512, 0, stream>>>(f);

    int grid_sums = 512;
    cluster_sums_kernel<<<grid_sums, BLOCK, 0, stream>>>(coords, margins, labels, n, f);

    compute_params_kernel<<<1, 64, 0, stream>>>(f);

    int chunks = n >> 2;
    int grid_main = (chunks + BLOCK - 1) / BLOCK;
    if (grid_main < 1) grid_main = 1;
    if (grid_main > 2048) grid_main = 2048;
    main_loss_kernel<<<grid_main, BLOCK, 0, stream>>>(emb, margins, seed, labels, n, f, acc);

    finalize_kernel<<<1, 1, 0, stream>>>(acc, out, n);
}